// Round 13
// baseline (1015.930 us; speedup 1.0000x reference)
//
#include <hip/hip_runtime.h>
#include <hip/hip_bf16.h>
#include <math.h>

#define KB 8
#define TT 8
#define HH 64
#define PHI_N 23
#define BOUNDF 5.0f
#define LN_P_OUT (-1.4469189829363254f)
#define HALF_LN_2PI 0.91893853320467274f
#define LOG2E 1.4426950408889634f
// softplus(SP_ONE) == 1.0 (to float precision); boundary-slope default
#define SP_ONE 0.54132485f

#define PHIS 32           // phiT row stride in floats (rows <=31; quad-XOR for banks)

typedef float f32x4 __attribute__((ext_vector_type(4)));
typedef short short8 __attribute__((ext_vector_type(8)));
typedef unsigned int u32x4 __attribute__((ext_vector_type(4)));

__device__ __forceinline__ unsigned short f2bf(float x) {
    __hip_bfloat16 h = __float2bfloat16(x);
    return __builtin_bit_cast(unsigned short, h);
}

// relu both + HW packed bf16 convert: 3 VALU (2 fmax + 1 v_cvt_pk_bf16_f32)
__device__ __forceinline__ unsigned int pk2(float a, float b) {
    float x = fmaxf(a, 0.f);
    float y = fmaxf(b, 0.f);
    unsigned int r;
    asm("v_cvt_pk_bf16_f32 %0, %1, %2" : "=v"(r) : "v"(x), "v"(y));
    return r;
}

// native exp2 (single v_exp_f32); inputs here are <= 0, range-safe
__device__ __forceinline__ float fexp2(float x) {
    float r;
    asm("v_exp_f32 %0, %1" : "=v"(r) : "v"(x));
    return r;
}

__device__ __forceinline__ float softplusf(float x) {
    return fmaxf(x, 0.f) + __logf(1.f + __expf(-fabsf(x)));
}

// Feature permutation: C-fragment position (tile m, row16=4g+r) holds feature
// P = 32*(m>>1) + 8*(row16>>2) + 4*(m&1) + (row16&3)  ==  B-slot k = 32kt+8g+i
// with kt=m>>1, i=4*(m&1)+r  ->  in-register layer transitions.
__device__ __forceinline__ int permF(int m, int r16) {
    return 32 * (m >> 1) + 8 * (r16 >> 2) + 4 * (m & 1) + (r16 & 3);
}

// ---------------- weight pack kernel ----------------
// Packed bf16 layout per t (8192 ushorts) as in R6-R12 (verified absmax 0.0),
// plus padded b3p[t][32] floats. NEW: W3/b3 rows 0..15 (widths+heights) are
// pre-scaled by log2(e) so the softmax exponentials become native exp2.
__global__ __launch_bounds__(256) void pack_weights(
    const float* __restrict__ W1, const float* __restrict__ b1,
    const float* __restrict__ W2, const float* __restrict__ W3,
    const float* __restrict__ b3g,
    unsigned short* __restrict__ packed,
    float* __restrict__ b3p)
{
    int gid = blockIdx.x * 256 + threadIdx.x;   // 0..65791
    if (gid < 65536) {
        int t = gid >> 13;
        int r = gid & 8191;
        float val = 0.f;
        if (r < 2048) {
            int m = r >> 9, l = (r >> 3) & 63, i = r & 7;
            int rowF = permF(m, l & 15);
            int k = 8 * (l >> 4) + i;
            if (k < 3) val = W1[t * 192 + k * 64 + rowF];
            else if (k == 3) val = b1[t * 64 + rowF];
        } else if (r < 6144) {
            int q = r - 2048;
            int kt = q >> 11; q &= 2047;
            int m = q >> 9, l = (q >> 3) & 63, i = q & 7;
            int rowF = permF(m, l & 15);
            int k = 32 * kt + 8 * (l >> 4) + i;
            val = W2[t * 4096 + k * 64 + rowF];
        } else {
            int q = r - 6144;
            int kt = q >> 10; q &= 1023;
            int mp = q >> 9, l = (q >> 3) & 63, i = q & 7;
            int row = 16 * mp + (l & 15);
            int k = 32 * kt + 8 * (l >> 4) + i;
            if (row < 23) {
                val = W3[t * 64 * PHI_N + k * PHI_N + row];
                if (row < 16) val *= LOG2E;     // widths+heights -> exp2 domain
            }
        }
        packed[gid] = f2bf(val);
    } else {
        int idx = gid - 65536;              // 0..255
        int t = idx >> 5, row = idx & 31;
        float v = (row < PHI_N) ? b3g[t * PHI_N + row] : 0.f;
        if (row < 16) v *= LOG2E;
        b3p[idx] = v;
    }
}

// ---------------- main kernel ----------------
// 4 independent waves per block, private phiT slices, no barriers/fences.
// This round: occupancy probe (bounds 256,5 -- LDS allows exactly 5 blocks/CU)
// + VALU cuts (exp2-domain softmax, constant boundary-slope defaults).
__global__ __launch_bounds__(256, 5) void gyro_main(
    const float* __restrict__ z_in,
    const float* __restrict__ log_age,
    const float* __restrict__ bprp0,
    const float* __restrict__ log_bprp0_err,
    const float* __restrict__ mem_prob,
    const float* __restrict__ b2g,
    const float* __restrict__ b3p,
    const unsigned short* __restrict__ packed,
    float* __restrict__ partials,
    int B)
{
    __shared__ float phiT_all[4 * 64 * PHIS];    // 32 KB, 8 KB per wave

    const int tid = threadIdx.x & 63;            // lane within wave
    const int wid = threadIdx.x >> 6;            // wave id in block
    const int c = tid & 15, g = tid >> 4;
    float* phiT = phiT_all + wid * 64 * PHIS;

    const int i = blockIdx.x * 256 + threadIdx.x;
    const bool active = (i < B);

    const float c0 = active ? log_age[i] : 0.f;
    const float c1 = active ? bprp0[i] : 0.f;
    const float c2 = active ? log_bprp0_err[i] : 0.f;
    float z = active ? z_in[i] : 0.f;
    const float pm_raw = active ? mem_prob[i] : 0.5f;

    // ---- ctx B-fragments: B[k][samp], nonzero only k=0..3 (lanes g==0) ----
    short8 bctx[4];
    #pragma unroll
    for (int n = 0; n < 4; ++n) {
        const int src = 16 * n + c;
        const float v0 = __shfl(c0, src);
        const float v1 = __shfl(c1, src);
        const float v2 = __shfl(c2, src);
        short8 f;
        f[0] = (short)f2bf(v0);
        f[1] = (short)f2bf(v1);
        f[2] = (short)f2bf(v2);
        f[3] = (short)0x3F80;   // bias slot (1.0)
        f[4] = 0; f[5] = 0; f[6] = 0; f[7] = 0;
        short8 zf = {0,0,0,0,0,0,0,0};
        bctx[n] = (g == 0) ? f : zf;
    }

    // preload t=0 L1 fragments (only cross-iteration weight state: 16 regs)
    short8 a1[4];
    #pragma unroll
    for (int m = 0; m < 4; ++m)
        a1[m] = *(const short8*)(packed + m * 512 + tid * 8);

    float logdet = 0.f;

    #pragma unroll 2
    for (int t = 0; t < TT; ++t) {
        const unsigned short* pt  = packed + t * 8192;
        const unsigned short* ptn = packed + (((t + 1) & 7) << 13);

        // ---- a2 loads for THIS t; latency covered by L1 compute below ----
        short8 a2[8];
        #pragma unroll
        for (int q = 0; q < 8; ++q)
            a2[q] = *(const short8*)(pt + 2048 + (q & 1) * 2048 + (q >> 1) * 512 + tid * 8);

        // ---- L1: h1^T = W1'^T ctx^T (+b1 folded), transition in-register ----
        short8 hb[2][4];
        #pragma unroll
        for (int n = 0; n < 4; ++n) {
            f32x4 C[4];
            #pragma unroll
            for (int m = 0; m < 4; ++m) {
                f32x4 zero = {0.f, 0.f, 0.f, 0.f};
                C[m] = __builtin_amdgcn_mfma_f32_16x16x32_bf16(a1[m], bctx[n], zero, 0, 0, 0);
            }
            #pragma unroll
            for (int kt = 0; kt < 2; ++kt) {
                u32x4 w;
                w[0] = pk2(C[2*kt][0],   C[2*kt][1]);
                w[1] = pk2(C[2*kt][2],   C[2*kt][3]);
                w[2] = pk2(C[2*kt+1][0], C[2*kt+1][1]);
                w[3] = pk2(C[2*kt+1][2], C[2*kt+1][3]);
                hb[kt][n] = __builtin_bit_cast(short8, w);
            }
        }

        // ---- a3 + bias loads; latency covered by L2's 16 MFMAs ----
        short8 a3[4];
        #pragma unroll
        for (int q = 0; q < 4; ++q)
            a3[q] = *(const short8*)(pt + 6144 + (q & 1) * 1024 + (q >> 1) * 512 + tid * 8);
        f32x4 b3v2[2];
        #pragma unroll
        for (int mp = 0; mp < 2; ++mp)
            b3v2[mp] = *(const f32x4*)(b3p + t * 32 + 16 * mp + 4 * g);

        // ---- L2: h2^T = W2'^T h1 + b2 (bias as MFMA C-init; no adds) ----
        short8 pb[2][4];
        #pragma unroll
        for (int ktp = 0; ktp < 2; ++ktp) {
            const f32x4 b2a = *(const f32x4*)(b2g + t * 64 + 32 * ktp + 8 * g);
            const f32x4 b2b = *(const f32x4*)(b2g + t * 64 + 32 * ktp + 8 * g + 4);
            #pragma unroll
            for (int n = 0; n < 4; ++n) {
                f32x4 u = __builtin_amdgcn_mfma_f32_16x16x32_bf16(a2[4*ktp + 0], hb[0][n], b2a, 0, 0, 0);
                u = __builtin_amdgcn_mfma_f32_16x16x32_bf16(a2[4*ktp + 1], hb[1][n], u, 0, 0, 0);
                f32x4 v = __builtin_amdgcn_mfma_f32_16x16x32_bf16(a2[4*ktp + 2], hb[0][n], b2b, 0, 0, 0);
                v = __builtin_amdgcn_mfma_f32_16x16x32_bf16(a2[4*ktp + 3], hb[1][n], v, 0, 0, 0);
                u32x4 w;
                w[0] = pk2(u[0], u[1]);
                w[1] = pk2(u[2], u[3]);
                w[2] = pk2(v[0], v[1]);
                w[3] = pk2(v[2], v[3]);
                pb[ktp][n] = __builtin_bit_cast(short8, w);
            }
        }

        // ---- prefetch next t's L1 fragments (covered by L3 + transpose + spline) ----
        #pragma unroll
        for (int m = 0; m < 4; ++m)
            a1[m] = *(const short8*)(ptn + m * 512 + tid * 8);

        // ---- L3: phi MFMAs (bias as C-init), written to LDS immediately ----
        #pragma unroll
        for (int mp = 0; mp < 2; ++mp) {
            const int q = (4 * mp + g) ^ (c & 7);
            #pragma unroll
            for (int n = 0; n < 4; ++n) {
                f32x4 acc = __builtin_amdgcn_mfma_f32_16x16x32_bf16(a3[2*mp + 0], pb[0][n], b3v2[mp], 0, 0, 0);
                acc = __builtin_amdgcn_mfma_f32_16x16x32_bf16(a3[2*mp + 1], pb[1][n], acc, 0, 0, 0);
                *(f32x4*)(phiT + (16 * n + c) * PHIS + q * 4) = acc;
            }
        }

        f32x4 pr[6];
        {
            const float* prow = phiT + tid * PHIS;
            #pragma unroll
            for (int s2 = 0; s2 < 6; ++s2)
                pr[s2] = *(const f32x4*)(prow + ((s2 ^ (tid & 7)) << 2));
        }
        float phi[PHI_N];
        #pragma unroll
        for (int j = 0; j < PHI_N; ++j) phi[j] = pr[j >> 2][j & 3];

        // ---- RQS spline forward (knot-free bin select, exp2-domain softmax) ----
        // phi[0..15] are pre-scaled by log2(e), so fexp2 gives exp(raw - max).
        float csx[KB + 1], csy[KB + 1];
        {
            float mx = phi[0];
            #pragma unroll
            for (int k = 1; k < KB; ++k) mx = fmaxf(mx, phi[k]);
            csx[0] = 0.f;
            #pragma unroll
            for (int k = 0; k < KB; ++k) csx[k + 1] = csx[k] + fexp2(phi[k] - mx);
        }
        {
            float my = phi[KB];
            #pragma unroll
            for (int k = 1; k < KB; ++k) my = fmaxf(my, phi[KB + k]);
            csy[0] = 0.f;
            #pragma unroll
            for (int k = 0; k < KB; ++k) csy[k + 1] = csy[k] + fexp2(phi[KB + k] - my);
        }
        const float sex = csx[KB], sey = csy[KB];
        const float invx = __builtin_amdgcn_rcpf(sex);
        const float invy = __builtin_amdgcn_rcpf(sey);

        const bool inside = fabsf(z) < BOUNDF;
        const float xc = fminf(fmaxf(z, -BOUNDF), BOUNDF);
        const float tau = (xc + BOUNDF) * sex * (0.5f / BOUNDF);

        float cx0 = 0.f, cx1 = csx[1];
        float cy0 = 0.f, cy1 = csy[1];
        float s0raw = SP_ONE;         // softplus(SP_ONE)=1 -> boundary slope
        float s1raw = phi[2 * KB];
        #pragma unroll
        for (int m = 1; m < KB; ++m) {
            const bool cc = (tau >= csx[m]);
            cx0 = cc ? csx[m]     : cx0;
            cx1 = cc ? csx[m + 1] : cx1;
            cy0 = cc ? csy[m]     : cy0;
            cy1 = cc ? csy[m + 1] : cy1;
            s0raw = cc ? phi[2 * KB + m - 1] : s0raw;
            s1raw = cc ? ((m < KB - 1) ? phi[2 * KB + m] : SP_ONE) : s1raw;
        }
        const float d0c = softplusf(s0raw);
        const float d1c = softplusf(s1raw);

        // materialize only the 4 winning knots
        const float px = 2.f * BOUNDF * invx;
        const float py = 2.f * BOUNDF * invy;
        const float x0 = fmaf(cx0, px, -BOUNDF);
        const float x1 = fmaf(cx1, px, -BOUNDF);
        const float y0 = fmaf(cy0, py, -BOUNDF);
        const float y1 = fmaf(cy1, py, -BOUNDF);

        const float rw   = __builtin_amdgcn_rcpf(x1 - x0);
        const float hk   = y1 - y0;
        const float s    = hk * rw;
        const float xi   = (xc - x0) * rw;
        const float xi1  = 1.f - xi;
        const float den  = s + (d1c + d0c - 2.f * s) * xi * xi1;
        const float rden = __builtin_amdgcn_rcpf(den);
        const float y    = y0 + hk * (s * xi * xi + d0c * xi * xi1) * rden;
        const float num  = d1c * xi * xi + 2.f * s * xi * xi1 + d0c * xi1 * xi1;
        const float ld   = __logf(s * s * num * rden * rden);   // 2log(s)+log(num)-2log(den)

        z = inside ? y : z;
        logdet += inside ? ld : 0.f;
    }

    float lc = 0.f;
    if (active) {
        const float logp = -0.5f * z * z - HALF_LN_2PI + logdet;
        float pm = pm_raw;
        pm = (pm != pm) ? 0.9f : pm;
        const float nfw = pm * 0.95f;
        const float a = __logf(nfw) + logp;
        const float b = __logf(1.f - nfw) + LN_P_OUT;
        const float mx2 = fmaxf(a, b);
        const float mn2 = fminf(a, b);
        lc = mx2 + __logf(1.f + __expf(mn2 - mx2));
    }

    // ---- within-wave deterministic reduction; one partial per wave ----
    double wsum = (double)lc;
    #pragma unroll
    for (int off = 32; off > 0; off >>= 1) wsum += __shfl_down(wsum, off, 64);
    if (tid == 0) partials[blockIdx.x * 4 + wid] = (float)wsum;
}

__global__ __launch_bounds__(256) void gyro_reduce(
    const float* __restrict__ partials, int n, float* __restrict__ out, int B)
{
    double s = 0.0;
    for (int i = threadIdx.x; i < n; i += 256) s += (double)partials[i];
    #pragma unroll
    for (int off = 32; off > 0; off >>= 1) s += __shfl_down(s, off, 64);

    __shared__ double sm[4];
    const int lane = threadIdx.x & 63;
    const int wid  = threadIdx.x >> 6;
    if (lane == 0) sm[wid] = s;
    __syncthreads();
    if (threadIdx.x == 0) {
        const double tot = sm[0] + sm[1] + sm[2] + sm[3];
        out[0] = (float)(-tot / (double)B);
    }
}

extern "C" void kernel_launch(void* const* d_in, const int* in_sizes, int n_in,
                              void* d_out, int out_size, void* d_ws, size_t ws_size,
                              hipStream_t stream) {
    const float* z_in   = (const float*)d_in[0];
    const float* lage   = (const float*)d_in[1];
    const float* bprp   = (const float*)d_in[2];
    const float* lberr  = (const float*)d_in[3];
    const float* memp   = (const float*)d_in[4];
    const float* W1     = (const float*)d_in[5];
    const float* b1     = (const float*)d_in[6];
    const float* W2     = (const float*)d_in[7];
    const float* b2     = (const float*)d_in[8];
    const float* W3     = (const float*)d_in[9];
    const float* b3     = (const float*)d_in[10];

    const int B = in_sizes[1];
    const int nblocks = (B + 255) / 256;

    unsigned short* packed = (unsigned short*)d_ws;                 // 131072 B
    float* b3p      = (float*)((char*)d_ws + 131072);               // 1024 B
    float* partials = (float*)((char*)d_ws + 132096);               // nblocks*4 floats

    pack_weights<<<257, 256, 0, stream>>>(W1, b1, W2, W3, b3, packed, b3p);
    gyro_main<<<nblocks, 256, 0, stream>>>(z_in, lage, bprp, lberr, memp,
                                           b2, b3p, packed, partials, B);
    gyro_reduce<<<1, 256, 0, stream>>>(partials, nblocks * 4, (float*)d_out, B);
}

// Round 14
// 356.000 us; speedup vs baseline: 2.8537x; 2.8537x over previous
//
#include <hip/hip_runtime.h>
#include <hip/hip_bf16.h>
#include <math.h>

#define KB 8
#define TT 8
#define HH 64
#define PHI_N 23
#define BOUNDF 5.0f
#define LN_P_OUT (-1.4469189829363254f)
#define HALF_LN_2PI 0.91893853320467274f
#define LOG2E 1.4426950408889634f
// softplus(SP_ONE) == 1.0 (to float precision); boundary-slope default
#define SP_ONE 0.54132485f

#define PHIS 32           // phiT row stride in floats (rows <=31; quad-XOR for banks)

typedef float f32x4 __attribute__((ext_vector_type(4)));
typedef short short8 __attribute__((ext_vector_type(8)));
typedef unsigned int u32x4 __attribute__((ext_vector_type(4)));

__device__ __forceinline__ unsigned short f2bf(float x) {
    __hip_bfloat16 h = __float2bfloat16(x);
    return __builtin_bit_cast(unsigned short, h);
}

// relu both + HW packed bf16 convert: 3 VALU (2 fmax + 1 v_cvt_pk_bf16_f32)
__device__ __forceinline__ unsigned int pk2(float a, float b) {
    float x = fmaxf(a, 0.f);
    float y = fmaxf(b, 0.f);
    unsigned int r;
    asm("v_cvt_pk_bf16_f32 %0, %1, %2" : "=v"(r) : "v"(x), "v"(y));
    return r;
}

// native exp2 (single v_exp_f32); inputs here are <= 0, range-safe
__device__ __forceinline__ float fexp2(float x) {
    float r;
    asm("v_exp_f32 %0, %1" : "=v"(r) : "v"(x));
    return r;
}

__device__ __forceinline__ float softplusf(float x) {
    return fmaxf(x, 0.f) + __logf(1.f + __expf(-fabsf(x)));
}

// Feature permutation: C-fragment position (tile m, row16=4g+r) holds feature
// P = 32*(m>>1) + 8*(row16>>2) + 4*(m&1) + (row16&3)  ==  B-slot k = 32kt+8g+i
// with kt=m>>1, i=4*(m&1)+r  ->  in-register layer transitions.
__device__ __forceinline__ int permF(int m, int r16) {
    return 32 * (m >> 1) + 8 * (r16 >> 2) + 4 * (m & 1) + (r16 & 3);
}

// ---------------- weight pack kernel ----------------
// Packed bf16 layout per t (8192 ushorts) as in R6-R13 (verified absmax 0.0),
// plus padded b3p[t][32] floats. W3/b3 rows 0..15 (widths+heights) are
// pre-scaled by log2(e) so the softmax exponentials become native exp2.
__global__ __launch_bounds__(256) void pack_weights(
    const float* __restrict__ W1, const float* __restrict__ b1,
    const float* __restrict__ W2, const float* __restrict__ W3,
    const float* __restrict__ b3g,
    unsigned short* __restrict__ packed,
    float* __restrict__ b3p)
{
    int gid = blockIdx.x * 256 + threadIdx.x;   // 0..65791
    if (gid < 65536) {
        int t = gid >> 13;
        int r = gid & 8191;
        float val = 0.f;
        if (r < 2048) {
            int m = r >> 9, l = (r >> 3) & 63, i = r & 7;
            int rowF = permF(m, l & 15);
            int k = 8 * (l >> 4) + i;
            if (k < 3) val = W1[t * 192 + k * 64 + rowF];
            else if (k == 3) val = b1[t * 64 + rowF];
        } else if (r < 6144) {
            int q = r - 2048;
            int kt = q >> 11; q &= 2047;
            int m = q >> 9, l = (q >> 3) & 63, i = q & 7;
            int rowF = permF(m, l & 15);
            int k = 32 * kt + 8 * (l >> 4) + i;
            val = W2[t * 4096 + k * 64 + rowF];
        } else {
            int q = r - 6144;
            int kt = q >> 10; q &= 1023;
            int mp = q >> 9, l = (q >> 3) & 63, i = q & 7;
            int row = 16 * mp + (l & 15);
            int k = 32 * kt + 8 * (l >> 4) + i;
            if (row < 23) {
                val = W3[t * 64 * PHI_N + k * PHI_N + row];
                if (row < 16) val *= LOG2E;     // widths+heights -> exp2 domain
            }
        }
        packed[gid] = f2bf(val);
    } else {
        int idx = gid - 65536;              // 0..255
        int t = idx >> 5, row = idx & 31;
        float v = (row < PHI_N) ? b3g[t * PHI_N + row] : 0.f;
        if (row < 16) v *= LOG2E;
        b3p[idx] = v;
    }
}

// ---------------- main kernel ----------------
// 4 independent waves per block, private phiT slices, no barriers/fences.
// launch_bounds REVERTED to (256,3): R13's (256,5) proved the ~102-reg cap
// forces spills (VGPR 48, 4.5 GB traffic); ~130-170 live regs is structural.
// Kept from R13: exp2-domain softmax + SP_ONE boundary defaults (VALU cuts).
__global__ __launch_bounds__(256, 3) void gyro_main(
    const float* __restrict__ z_in,
    const float* __restrict__ log_age,
    const float* __restrict__ bprp0,
    const float* __restrict__ log_bprp0_err,
    const float* __restrict__ mem_prob,
    const float* __restrict__ b2g,
    const float* __restrict__ b3p,
    const unsigned short* __restrict__ packed,
    float* __restrict__ partials,
    int B)
{
    __shared__ float phiT_all[4 * 64 * PHIS];    // 32 KB, 8 KB per wave

    const int tid = threadIdx.x & 63;            // lane within wave
    const int wid = threadIdx.x >> 6;            // wave id in block
    const int c = tid & 15, g = tid >> 4;
    float* phiT = phiT_all + wid * 64 * PHIS;

    const int i = blockIdx.x * 256 + threadIdx.x;
    const bool active = (i < B);

    const float c0 = active ? log_age[i] : 0.f;
    const float c1 = active ? bprp0[i] : 0.f;
    const float c2 = active ? log_bprp0_err[i] : 0.f;
    float z = active ? z_in[i] : 0.f;
    const float pm_raw = active ? mem_prob[i] : 0.5f;

    // ---- ctx B-fragments: B[k][samp], nonzero only k=0..3 (lanes g==0) ----
    short8 bctx[4];
    #pragma unroll
    for (int n = 0; n < 4; ++n) {
        const int src = 16 * n + c;
        const float v0 = __shfl(c0, src);
        const float v1 = __shfl(c1, src);
        const float v2 = __shfl(c2, src);
        short8 f;
        f[0] = (short)f2bf(v0);
        f[1] = (short)f2bf(v1);
        f[2] = (short)f2bf(v2);
        f[3] = (short)0x3F80;   // bias slot (1.0)
        f[4] = 0; f[5] = 0; f[6] = 0; f[7] = 0;
        short8 zf = {0,0,0,0,0,0,0,0};
        bctx[n] = (g == 0) ? f : zf;
    }

    // preload t=0 L1 fragments (only cross-iteration weight state: 16 regs)
    short8 a1[4];
    #pragma unroll
    for (int m = 0; m < 4; ++m)
        a1[m] = *(const short8*)(packed + m * 512 + tid * 8);

    float logdet = 0.f;

    #pragma unroll 2
    for (int t = 0; t < TT; ++t) {
        const unsigned short* pt  = packed + t * 8192;
        const unsigned short* ptn = packed + (((t + 1) & 7) << 13);

        // ---- a2 loads for THIS t; latency covered by L1 compute below ----
        short8 a2[8];
        #pragma unroll
        for (int q = 0; q < 8; ++q)
            a2[q] = *(const short8*)(pt + 2048 + (q & 1) * 2048 + (q >> 1) * 512 + tid * 8);

        // ---- L1: h1^T = W1'^T ctx^T (+b1 folded), transition in-register ----
        short8 hb[2][4];
        #pragma unroll
        for (int n = 0; n < 4; ++n) {
            f32x4 C[4];
            #pragma unroll
            for (int m = 0; m < 4; ++m) {
                f32x4 zero = {0.f, 0.f, 0.f, 0.f};
                C[m] = __builtin_amdgcn_mfma_f32_16x16x32_bf16(a1[m], bctx[n], zero, 0, 0, 0);
            }
            #pragma unroll
            for (int kt = 0; kt < 2; ++kt) {
                u32x4 w;
                w[0] = pk2(C[2*kt][0],   C[2*kt][1]);
                w[1] = pk2(C[2*kt][2],   C[2*kt][3]);
                w[2] = pk2(C[2*kt+1][0], C[2*kt+1][1]);
                w[3] = pk2(C[2*kt+1][2], C[2*kt+1][3]);
                hb[kt][n] = __builtin_bit_cast(short8, w);
            }
        }

        // ---- a3 + bias loads; latency covered by L2's 16 MFMAs ----
        short8 a3[4];
        #pragma unroll
        for (int q = 0; q < 4; ++q)
            a3[q] = *(const short8*)(pt + 6144 + (q & 1) * 1024 + (q >> 1) * 512 + tid * 8);
        f32x4 b3v2[2];
        #pragma unroll
        for (int mp = 0; mp < 2; ++mp)
            b3v2[mp] = *(const f32x4*)(b3p + t * 32 + 16 * mp + 4 * g);

        // ---- L2: h2^T = W2'^T h1 + b2 (bias as MFMA C-init; no adds) ----
        short8 pb[2][4];
        #pragma unroll
        for (int ktp = 0; ktp < 2; ++ktp) {
            const f32x4 b2a = *(const f32x4*)(b2g + t * 64 + 32 * ktp + 8 * g);
            const f32x4 b2b = *(const f32x4*)(b2g + t * 64 + 32 * ktp + 8 * g + 4);
            #pragma unroll
            for (int n = 0; n < 4; ++n) {
                f32x4 u = __builtin_amdgcn_mfma_f32_16x16x32_bf16(a2[4*ktp + 0], hb[0][n], b2a, 0, 0, 0);
                u = __builtin_amdgcn_mfma_f32_16x16x32_bf16(a2[4*ktp + 1], hb[1][n], u, 0, 0, 0);
                f32x4 v = __builtin_amdgcn_mfma_f32_16x16x32_bf16(a2[4*ktp + 2], hb[0][n], b2b, 0, 0, 0);
                v = __builtin_amdgcn_mfma_f32_16x16x32_bf16(a2[4*ktp + 3], hb[1][n], v, 0, 0, 0);
                u32x4 w;
                w[0] = pk2(u[0], u[1]);
                w[1] = pk2(u[2], u[3]);
                w[2] = pk2(v[0], v[1]);
                w[3] = pk2(v[2], v[3]);
                pb[ktp][n] = __builtin_bit_cast(short8, w);
            }
        }

        // ---- prefetch next t's L1 fragments (covered by L3 + transpose + spline) ----
        #pragma unroll
        for (int m = 0; m < 4; ++m)
            a1[m] = *(const short8*)(ptn + m * 512 + tid * 8);

        // ---- L3: phi MFMAs (bias as C-init), written to LDS immediately ----
        #pragma unroll
        for (int mp = 0; mp < 2; ++mp) {
            const int q = (4 * mp + g) ^ (c & 7);
            #pragma unroll
            for (int n = 0; n < 4; ++n) {
                f32x4 acc = __builtin_amdgcn_mfma_f32_16x16x32_bf16(a3[2*mp + 0], pb[0][n], b3v2[mp], 0, 0, 0);
                acc = __builtin_amdgcn_mfma_f32_16x16x32_bf16(a3[2*mp + 1], pb[1][n], acc, 0, 0, 0);
                *(f32x4*)(phiT + (16 * n + c) * PHIS + q * 4) = acc;
            }
        }

        f32x4 pr[6];
        {
            const float* prow = phiT + tid * PHIS;
            #pragma unroll
            for (int s2 = 0; s2 < 6; ++s2)
                pr[s2] = *(const f32x4*)(prow + ((s2 ^ (tid & 7)) << 2));
        }
        float phi[PHI_N];
        #pragma unroll
        for (int j = 0; j < PHI_N; ++j) phi[j] = pr[j >> 2][j & 3];

        // ---- RQS spline forward (knot-free bin select, exp2-domain softmax) ----
        // phi[0..15] are pre-scaled by log2(e), so fexp2 gives exp(raw - max).
        float csx[KB + 1], csy[KB + 1];
        {
            float mx = phi[0];
            #pragma unroll
            for (int k = 1; k < KB; ++k) mx = fmaxf(mx, phi[k]);
            csx[0] = 0.f;
            #pragma unroll
            for (int k = 0; k < KB; ++k) csx[k + 1] = csx[k] + fexp2(phi[k] - mx);
        }
        {
            float my = phi[KB];
            #pragma unroll
            for (int k = 1; k < KB; ++k) my = fmaxf(my, phi[KB + k]);
            csy[0] = 0.f;
            #pragma unroll
            for (int k = 0; k < KB; ++k) csy[k + 1] = csy[k] + fexp2(phi[KB + k] - my);
        }
        const float sex = csx[KB], sey = csy[KB];
        const float invx = __builtin_amdgcn_rcpf(sex);
        const float invy = __builtin_amdgcn_rcpf(sey);

        const bool inside = fabsf(z) < BOUNDF;
        const float xc = fminf(fmaxf(z, -BOUNDF), BOUNDF);
        const float tau = (xc + BOUNDF) * sex * (0.5f / BOUNDF);

        float cx0 = 0.f, cx1 = csx[1];
        float cy0 = 0.f, cy1 = csy[1];
        float s0raw = SP_ONE;         // softplus(SP_ONE)=1 -> boundary slope
        float s1raw = phi[2 * KB];
        #pragma unroll
        for (int m = 1; m < KB; ++m) {
            const bool cc = (tau >= csx[m]);
            cx0 = cc ? csx[m]     : cx0;
            cx1 = cc ? csx[m + 1] : cx1;
            cy0 = cc ? csy[m]     : cy0;
            cy1 = cc ? csy[m + 1] : cy1;
            s0raw = cc ? phi[2 * KB + m - 1] : s0raw;
            s1raw = cc ? ((m < KB - 1) ? phi[2 * KB + m] : SP_ONE) : s1raw;
        }
        const float d0c = softplusf(s0raw);
        const float d1c = softplusf(s1raw);

        // materialize only the 4 winning knots
        const float px = 2.f * BOUNDF * invx;
        const float py = 2.f * BOUNDF * invy;
        const float x0 = fmaf(cx0, px, -BOUNDF);
        const float x1 = fmaf(cx1, px, -BOUNDF);
        const float y0 = fmaf(cy0, py, -BOUNDF);
        const float y1 = fmaf(cy1, py, -BOUNDF);

        const float rw   = __builtin_amdgcn_rcpf(x1 - x0);
        const float hk   = y1 - y0;
        const float s    = hk * rw;
        const float xi   = (xc - x0) * rw;
        const float xi1  = 1.f - xi;
        const float den  = s + (d1c + d0c - 2.f * s) * xi * xi1;
        const float rden = __builtin_amdgcn_rcpf(den);
        const float y    = y0 + hk * (s * xi * xi + d0c * xi * xi1) * rden;
        const float num  = d1c * xi * xi + 2.f * s * xi * xi1 + d0c * xi1 * xi1;
        const float ld   = __logf(s * s * num * rden * rden);   // 2log(s)+log(num)-2log(den)

        z = inside ? y : z;
        logdet += inside ? ld : 0.f;
    }

    float lc = 0.f;
    if (active) {
        const float logp = -0.5f * z * z - HALF_LN_2PI + logdet;
        float pm = pm_raw;
        pm = (pm != pm) ? 0.9f : pm;
        const float nfw = pm * 0.95f;
        const float a = __logf(nfw) + logp;
        const float b = __logf(1.f - nfw) + LN_P_OUT;
        const float mx2 = fmaxf(a, b);
        const float mn2 = fminf(a, b);
        lc = mx2 + __logf(1.f + __expf(mn2 - mx2));
    }

    // ---- within-wave deterministic reduction; one partial per wave ----
    double wsum = (double)lc;
    #pragma unroll
    for (int off = 32; off > 0; off >>= 1) wsum += __shfl_down(wsum, off, 64);
    if (tid == 0) partials[blockIdx.x * 4 + wid] = (float)wsum;
}

__global__ __launch_bounds__(256) void gyro_reduce(
    const float* __restrict__ partials, int n, float* __restrict__ out, int B)
{
    double s = 0.0;
    for (int i = threadIdx.x; i < n; i += 256) s += (double)partials[i];
    #pragma unroll
    for (int off = 32; off > 0; off >>= 1) s += __shfl_down(s, off, 64);

    __shared__ double sm[4];
    const int lane = threadIdx.x & 63;
    const int wid  = threadIdx.x >> 6;
    if (lane == 0) sm[wid] = s;
    __syncthreads();
    if (threadIdx.x == 0) {
        const double tot = sm[0] + sm[1] + sm[2] + sm[3];
        out[0] = (float)(-tot / (double)B);
    }
}

extern "C" void kernel_launch(void* const* d_in, const int* in_sizes, int n_in,
                              void* d_out, int out_size, void* d_ws, size_t ws_size,
                              hipStream_t stream) {
    const float* z_in   = (const float*)d_in[0];
    const float* lage   = (const float*)d_in[1];
    const float* bprp   = (const float*)d_in[2];
    const float* lberr  = (const float*)d_in[3];
    const float* memp   = (const float*)d_in[4];
    const float* W1     = (const float*)d_in[5];
    const float* b1     = (const float*)d_in[6];
    const float* W2     = (const float*)d_in[7];
    const float* b2     = (const float*)d_in[8];
    const float* W3     = (const float*)d_in[9];
    const float* b3     = (const float*)d_in[10];

    const int B = in_sizes[1];
    const int nblocks = (B + 255) / 256;

    unsigned short* packed = (unsigned short*)d_ws;                 // 131072 B
    float* b3p      = (float*)((char*)d_ws + 131072);               // 1024 B
    float* partials = (float*)((char*)d_ws + 132096);               // nblocks*4 floats

    pack_weights<<<257, 256, 0, stream>>>(W1, b1, W2, W3, b3, packed, b3p);
    gyro_main<<<nblocks, 256, 0, stream>>>(z_in, lage, bprp, lberr, memp,
                                           b2, b3p, packed, partials, B);
    gyro_reduce<<<1, 256, 0, stream>>>(partials, nblocks * 4, (float*)d_out, B);
}

// Round 15
// 354.375 us; speedup vs baseline: 2.8668x; 1.0046x over previous
//
#include <hip/hip_runtime.h>
#include <hip/hip_bf16.h>
#include <math.h>

#define KB 8
#define TT 8
#define HH 64
#define PHI_N 23
#define BOUNDF 5.0f
#define LN_P_OUT (-1.4469189829363254f)
#define HALF_LN_2PI 0.91893853320467274f
#define LOG2E 1.4426950408889634f
// softplus(SP_ONE) == 1.0 (to float precision); boundary-slope default
#define SP_ONE 0.54132485f

#define PHIS 32           // phiT row stride in floats (rows <=31; quad-XOR for banks)

typedef float f32x4 __attribute__((ext_vector_type(4)));
typedef short short8 __attribute__((ext_vector_type(8)));
typedef unsigned int u32x4 __attribute__((ext_vector_type(4)));

__device__ __forceinline__ unsigned short f2bf(float x) {
    __hip_bfloat16 h = __float2bfloat16(x);
    return __builtin_bit_cast(unsigned short, h);
}

// relu both + HW packed bf16 convert: 3 VALU (2 fmax + 1 v_cvt_pk_bf16_f32)
__device__ __forceinline__ unsigned int pk2(float a, float b) {
    float x = fmaxf(a, 0.f);
    float y = fmaxf(b, 0.f);
    unsigned int r;
    asm("v_cvt_pk_bf16_f32 %0, %1, %2" : "=v"(r) : "v"(x), "v"(y));
    return r;
}

// native exp2 (single v_exp_f32); inputs here are <= 0, range-safe
__device__ __forceinline__ float fexp2(float x) {
    float r;
    asm("v_exp_f32 %0, %1" : "=v"(r) : "v"(x));
    return r;
}

__device__ __forceinline__ float softplusf(float x) {
    return fmaxf(x, 0.f) + __logf(1.f + __expf(-fabsf(x)));
}

// Feature permutation: C-fragment position (tile m, row16=4g+r) holds feature
// P = 32*(m>>1) + 8*(row16>>2) + 4*(m&1) + (row16&3)  ==  B-slot k = 32kt+8g+i
// with kt=m>>1, i=4*(m&1)+r  ->  in-register layer transitions.
__device__ __forceinline__ int permF(int m, int r16) {
    return 32 * (m >> 1) + 8 * (r16 >> 2) + 4 * (m & 1) + (r16 & 3);
}

// ---------------- weight pack kernel ----------------
// Packed bf16 layout per t (8192 ushorts) as in R6-R14 (verified absmax 0.0),
// plus padded b3p[t][32] floats. W3/b3 rows 0..15 (widths+heights) are
// pre-scaled by log2(e) so the softmax exponentials become native exp2.
__global__ __launch_bounds__(256) void pack_weights(
    const float* __restrict__ W1, const float* __restrict__ b1,
    const float* __restrict__ W2, const float* __restrict__ W3,
    const float* __restrict__ b3g,
    unsigned short* __restrict__ packed,
    float* __restrict__ b3p)
{
    int gid = blockIdx.x * 256 + threadIdx.x;   // 0..65791
    if (gid < 65536) {
        int t = gid >> 13;
        int r = gid & 8191;
        float val = 0.f;
        if (r < 2048) {
            int m = r >> 9, l = (r >> 3) & 63, i = r & 7;
            int rowF = permF(m, l & 15);
            int k = 8 * (l >> 4) + i;
            if (k < 3) val = W1[t * 192 + k * 64 + rowF];
            else if (k == 3) val = b1[t * 64 + rowF];
        } else if (r < 6144) {
            int q = r - 2048;
            int kt = q >> 11; q &= 2047;
            int m = q >> 9, l = (q >> 3) & 63, i = q & 7;
            int rowF = permF(m, l & 15);
            int k = 32 * kt + 8 * (l >> 4) + i;
            val = W2[t * 4096 + k * 64 + rowF];
        } else {
            int q = r - 6144;
            int kt = q >> 10; q &= 1023;
            int mp = q >> 9, l = (q >> 3) & 63, i = q & 7;
            int row = 16 * mp + (l & 15);
            int k = 32 * kt + 8 * (l >> 4) + i;
            if (row < 23) {
                val = W3[t * 64 * PHI_N + k * PHI_N + row];
                if (row < 16) val *= LOG2E;     // widths+heights -> exp2 domain
            }
        }
        packed[gid] = f2bf(val);
    } else {
        int idx = gid - 65536;              // 0..255
        int t = idx >> 5, row = idx & 31;
        float v = (row < PHI_N) ? b3g[t * PHI_N + row] : 0.f;
        if (row < 16) v *= LOG2E;
        b3p[idx] = v;
    }
}

// ---- one transform's MLP: ctx -> phi, written transposed to wave-private LDS ----
__device__ __forceinline__ void mlp_to_lds(
    const unsigned short* __restrict__ pt,
    const unsigned short* __restrict__ ptn,
    const float* __restrict__ b2t,      // b2g + t*64
    const float* __restrict__ b3t,      // b3p + t*32
    short8 (&a1)[4], const short8 (&bctx)[4],
    float* __restrict__ phiT, int tid, int c, int g)
{
    // a2 loads; latency covered by L1 compute below
    short8 a2[8];
    #pragma unroll
    for (int q = 0; q < 8; ++q)
        a2[q] = *(const short8*)(pt + 2048 + (q & 1) * 2048 + (q >> 1) * 512 + tid * 8);

    // L1: h1^T = W1'^T ctx^T (+b1 folded), transition in-register
    short8 hb[2][4];
    #pragma unroll
    for (int n = 0; n < 4; ++n) {
        f32x4 C[4];
        #pragma unroll
        for (int m = 0; m < 4; ++m) {
            f32x4 zero = {0.f, 0.f, 0.f, 0.f};
            C[m] = __builtin_amdgcn_mfma_f32_16x16x32_bf16(a1[m], bctx[n], zero, 0, 0, 0);
        }
        #pragma unroll
        for (int kt = 0; kt < 2; ++kt) {
            u32x4 w;
            w[0] = pk2(C[2*kt][0],   C[2*kt][1]);
            w[1] = pk2(C[2*kt][2],   C[2*kt][3]);
            w[2] = pk2(C[2*kt+1][0], C[2*kt+1][1]);
            w[3] = pk2(C[2*kt+1][2], C[2*kt+1][3]);
            hb[kt][n] = __builtin_bit_cast(short8, w);
        }
    }

    // a3 + bias loads; latency covered by L2's MFMAs
    short8 a3[4];
    #pragma unroll
    for (int q = 0; q < 4; ++q)
        a3[q] = *(const short8*)(pt + 6144 + (q & 1) * 1024 + (q >> 1) * 512 + tid * 8);
    f32x4 b3v2[2];
    #pragma unroll
    for (int mp = 0; mp < 2; ++mp)
        b3v2[mp] = *(const f32x4*)(b3t + 16 * mp + 4 * g);

    // L2: h2^T = W2'^T h1 + b2 (bias as MFMA C-init)
    short8 pb[2][4];
    #pragma unroll
    for (int ktp = 0; ktp < 2; ++ktp) {
        const f32x4 b2a = *(const f32x4*)(b2t + 32 * ktp + 8 * g);
        const f32x4 b2b = *(const f32x4*)(b2t + 32 * ktp + 8 * g + 4);
        #pragma unroll
        for (int n = 0; n < 4; ++n) {
            f32x4 u = __builtin_amdgcn_mfma_f32_16x16x32_bf16(a2[4*ktp + 0], hb[0][n], b2a, 0, 0, 0);
            u = __builtin_amdgcn_mfma_f32_16x16x32_bf16(a2[4*ktp + 1], hb[1][n], u, 0, 0, 0);
            f32x4 v = __builtin_amdgcn_mfma_f32_16x16x32_bf16(a2[4*ktp + 2], hb[0][n], b2b, 0, 0, 0);
            v = __builtin_amdgcn_mfma_f32_16x16x32_bf16(a2[4*ktp + 3], hb[1][n], v, 0, 0, 0);
            u32x4 w;
            w[0] = pk2(u[0], u[1]);
            w[1] = pk2(u[2], u[3]);
            w[2] = pk2(v[0], v[1]);
            w[3] = pk2(v[2], v[3]);
            pb[ktp][n] = __builtin_bit_cast(short8, w);
        }
    }

    // prefetch next t's L1 fragments (covered by L3 + the caller's spline)
    #pragma unroll
    for (int m = 0; m < 4; ++m)
        a1[m] = *(const short8*)(ptn + m * 512 + tid * 8);

    // L3: phi MFMAs (bias as C-init), written to LDS immediately
    #pragma unroll
    for (int mp = 0; mp < 2; ++mp) {
        const int q = (4 * mp + g) ^ (c & 7);
        #pragma unroll
        for (int n = 0; n < 4; ++n) {
            f32x4 acc = __builtin_amdgcn_mfma_f32_16x16x32_bf16(a3[2*mp + 0], pb[0][n], b3v2[mp], 0, 0, 0);
            acc = __builtin_amdgcn_mfma_f32_16x16x32_bf16(a3[2*mp + 1], pb[1][n], acc, 0, 0, 0);
            *(f32x4*)(phiT + (16 * n + c) * PHIS + q * 4) = acc;
        }
    }
}

__device__ __forceinline__ void read_phi(
    const float* __restrict__ phiT, int tid, f32x4 (&pr)[6])
{
    const float* prow = phiT + tid * PHIS;
    #pragma unroll
    for (int s2 = 0; s2 < 6; ++s2)
        pr[s2] = *(const f32x4*)(prow + ((s2 ^ (tid & 7)) << 2));
}

// ---- RQS spline forward on registers (knot-free select, exp2-domain softmax) ----
__device__ __forceinline__ void spline_step(
    const f32x4 (&pr)[6], float& z, float& logdet)
{
    float phi[PHI_N];
    #pragma unroll
    for (int j = 0; j < PHI_N; ++j) phi[j] = pr[j >> 2][j & 3];

    float csx[KB + 1], csy[KB + 1];
    {
        float mx = phi[0];
        #pragma unroll
        for (int k = 1; k < KB; ++k) mx = fmaxf(mx, phi[k]);
        csx[0] = 0.f;
        #pragma unroll
        for (int k = 0; k < KB; ++k) csx[k + 1] = csx[k] + fexp2(phi[k] - mx);
    }
    {
        float my = phi[KB];
        #pragma unroll
        for (int k = 1; k < KB; ++k) my = fmaxf(my, phi[KB + k]);
        csy[0] = 0.f;
        #pragma unroll
        for (int k = 0; k < KB; ++k) csy[k + 1] = csy[k] + fexp2(phi[KB + k] - my);
    }
    const float sex = csx[KB], sey = csy[KB];
    const float invx = __builtin_amdgcn_rcpf(sex);
    const float invy = __builtin_amdgcn_rcpf(sey);

    const bool inside = fabsf(z) < BOUNDF;
    const float xc = fminf(fmaxf(z, -BOUNDF), BOUNDF);
    const float tau = (xc + BOUNDF) * sex * (0.5f / BOUNDF);

    float cx0 = 0.f, cx1 = csx[1];
    float cy0 = 0.f, cy1 = csy[1];
    float s0raw = SP_ONE;         // softplus(SP_ONE)=1 -> boundary slope
    float s1raw = phi[2 * KB];
    #pragma unroll
    for (int m = 1; m < KB; ++m) {
        const bool cc = (tau >= csx[m]);
        cx0 = cc ? csx[m]     : cx0;
        cx1 = cc ? csx[m + 1] : cx1;
        cy0 = cc ? csy[m]     : cy0;
        cy1 = cc ? csy[m + 1] : cy1;
        s0raw = cc ? phi[2 * KB + m - 1] : s0raw;
        s1raw = cc ? ((m < KB - 1) ? phi[2 * KB + m] : SP_ONE) : s1raw;
    }
    const float d0c = softplusf(s0raw);
    const float d1c = softplusf(s1raw);

    const float px = 2.f * BOUNDF * invx;
    const float py = 2.f * BOUNDF * invy;
    const float x0 = fmaf(cx0, px, -BOUNDF);
    const float x1 = fmaf(cx1, px, -BOUNDF);
    const float y0 = fmaf(cy0, py, -BOUNDF);
    const float y1 = fmaf(cy1, py, -BOUNDF);

    const float rw   = __builtin_amdgcn_rcpf(x1 - x0);
    const float hk   = y1 - y0;
    const float s    = hk * rw;
    const float xi   = (xc - x0) * rw;
    const float xi1  = 1.f - xi;
    const float den  = s + (d1c + d0c - 2.f * s) * xi * xi1;
    const float rden = __builtin_amdgcn_rcpf(den);
    const float y    = y0 + hk * (s * xi * xi + d0c * xi * xi1) * rden;
    const float num  = d1c * xi * xi + 2.f * s * xi * xi1 + d0c * xi1 * xi1;
    const float ld   = __logf(s * s * num * rden * rden);

    z = inside ? y : z;
    logdet += inside ? ld : 0.f;
}

// ---------------- main kernel ----------------
// 4 independent waves per block, private phiT slices, no barriers/fences.
// SOFTWARE PIPELINE: spline(t-1) runs from registers INSIDE the same
// scheduling region as MLP(t) (which is z-independent) -- the spline's ~150
// VALU ops fill MLP's load/MFMA stall slots, and the phi(t) LDS write->read
// latency is covered by the whole spline. Register cost: +24 (pr[6]).
__global__ __launch_bounds__(256, 3) void gyro_main(
    const float* __restrict__ z_in,
    const float* __restrict__ log_age,
    const float* __restrict__ bprp0,
    const float* __restrict__ log_bprp0_err,
    const float* __restrict__ mem_prob,
    const float* __restrict__ b2g,
    const float* __restrict__ b3p,
    const unsigned short* __restrict__ packed,
    float* __restrict__ partials,
    int B)
{
    __shared__ float phiT_all[4 * 64 * PHIS];    // 32 KB, 8 KB per wave

    const int tid = threadIdx.x & 63;            // lane within wave
    const int wid = threadIdx.x >> 6;            // wave id in block
    const int c = tid & 15, g = tid >> 4;
    float* phiT = phiT_all + wid * 64 * PHIS;

    const int i = blockIdx.x * 256 + threadIdx.x;
    const bool active = (i < B);

    const float c0 = active ? log_age[i] : 0.f;
    const float c1 = active ? bprp0[i] : 0.f;
    const float c2 = active ? log_bprp0_err[i] : 0.f;
    float z = active ? z_in[i] : 0.f;
    const float pm_raw = active ? mem_prob[i] : 0.5f;

    // ---- ctx B-fragments: B[k][samp], nonzero only k=0..3 (lanes g==0) ----
    short8 bctx[4];
    #pragma unroll
    for (int n = 0; n < 4; ++n) {
        const int src = 16 * n + c;
        const float v0 = __shfl(c0, src);
        const float v1 = __shfl(c1, src);
        const float v2 = __shfl(c2, src);
        short8 f;
        f[0] = (short)f2bf(v0);
        f[1] = (short)f2bf(v1);
        f[2] = (short)f2bf(v2);
        f[3] = (short)0x3F80;   // bias slot (1.0)
        f[4] = 0; f[5] = 0; f[6] = 0; f[7] = 0;
        short8 zf = {0,0,0,0,0,0,0,0};
        bctx[n] = (g == 0) ? f : zf;
    }

    // preload t=0 L1 fragments
    short8 a1[4];
    #pragma unroll
    for (int m = 0; m < 4; ++m)
        a1[m] = *(const short8*)(packed + m * 512 + tid * 8);

    float logdet = 0.f;

    // ---- prologue: MLP(0) -> phiT, read phi(0) into registers ----
    mlp_to_lds(packed, packed + 8192, b2g, b3p, a1, bctx, phiT, tid, c, g);
    f32x4 pr[6];
    read_phi(phiT, tid, pr);

    // ---- pipelined main loop: MLP(t) || spline(t-1) ----
    #pragma unroll 1
    for (int t = 1; t < TT; ++t) {
        const unsigned short* pt  = packed + t * 8192;
        const unsigned short* ptn = packed + (((t + 1) & 7) << 13);
        mlp_to_lds(pt, ptn, b2g + t * 64, b3p + t * 32, a1, bctx, phiT, tid, c, g);
        spline_step(pr, z, logdet);      // phi(t-1), independent of MLP(t)
        read_phi(phiT, tid, pr);         // phi(t); LDS latency covered by spline
    }
    // ---- epilogue: spline(7) ----
    spline_step(pr, z, logdet);

    float lc = 0.f;
    if (active) {
        const float logp = -0.5f * z * z - HALF_LN_2PI + logdet;
        float pm = pm_raw;
        pm = (pm != pm) ? 0.9f : pm;
        const float nfw = pm * 0.95f;
        const float a = __logf(nfw) + logp;
        const float b = __logf(1.f - nfw) + LN_P_OUT;
        const float mx2 = fmaxf(a, b);
        const float mn2 = fminf(a, b);
        lc = mx2 + __logf(1.f + __expf(mn2 - mx2));
    }

    // ---- within-wave deterministic reduction; one partial per wave ----
    double wsum = (double)lc;
    #pragma unroll
    for (int off = 32; off > 0; off >>= 1) wsum += __shfl_down(wsum, off, 64);
    if (tid == 0) partials[blockIdx.x * 4 + wid] = (float)wsum;
}

__global__ __launch_bounds__(256) void gyro_reduce(
    const float* __restrict__ partials, int n, float* __restrict__ out, int B)
{
    double s = 0.0;
    for (int i = threadIdx.x; i < n; i += 256) s += (double)partials[i];
    #pragma unroll
    for (int off = 32; off > 0; off >>= 1) s += __shfl_down(s, off, 64);

    __shared__ double sm[4];
    const int lane = threadIdx.x & 63;
    const int wid  = threadIdx.x >> 6;
    if (lane == 0) sm[wid] = s;
    __syncthreads();
    if (threadIdx.x == 0) {
        const double tot = sm[0] + sm[1] + sm[2] + sm[3];
        out[0] = (float)(-tot / (double)B);
    }
}

extern "C" void kernel_launch(void* const* d_in, const int* in_sizes, int n_in,
                              void* d_out, int out_size, void* d_ws, size_t ws_size,
                              hipStream_t stream) {
    const float* z_in   = (const float*)d_in[0];
    const float* lage   = (const float*)d_in[1];
    const float* bprp   = (const float*)d_in[2];
    const float* lberr  = (const float*)d_in[3];
    const float* memp   = (const float*)d_in[4];
    const float* W1     = (const float*)d_in[5];
    const float* b1     = (const float*)d_in[6];
    const float* W2     = (const float*)d_in[7];
    const float* b2     = (const float*)d_in[8];
    const float* W3     = (const float*)d_in[9];
    const float* b3     = (const float*)d_in[10];

    const int B = in_sizes[1];
    const int nblocks = (B + 255) / 256;

    unsigned short* packed = (unsigned short*)d_ws;                 // 131072 B
    float* b3p      = (float*)((char*)d_ws + 131072);               // 1024 B
    float* partials = (float*)((char*)d_ws + 132096);               // nblocks*4 floats

    pack_weights<<<257, 256, 0, stream>>>(W1, b1, W2, W3, b3, packed, b3p);
    gyro_main<<<nblocks, 256, 0, stream>>>(z_in, lage, bprp, lberr, memp,
                                           b2, b3p, packed, partials, B);
    gyro_reduce<<<1, 256, 0, stream>>>(partials, nblocks * 4, (float*)d_out, B);
}